// Round 1
// baseline (816.510 us; speedup 1.0000x reference)
//
#include <hip/hip_runtime.h>

typedef float  f32x4  __attribute__((ext_vector_type(4)));
typedef short  bf16x8 __attribute__((ext_vector_type(8)));
typedef unsigned short u16x4 __attribute__((ext_vector_type(4)));

#define MFMA16(a,b,c) __builtin_amdgcn_mfma_f32_16x16x32_bf16((a),(b),(c),0,0,0)

__device__ __forceinline__ unsigned short f2bf(float f){
  unsigned u = __float_as_uint(f);
  u += 0x7fffu + ((u>>16)&1u);            // RNE
  return (unsigned short)(u>>16);
}
__device__ __forceinline__ float bf2f(unsigned short u){
  return __uint_as_float(((unsigned)u)<<16);
}
__device__ __forceinline__ float sigm(float x){
  return __fdividef(1.f, 1.f + __expf(-x));
}
__device__ __forceinline__ float tanhfast(float x){
  return 1.f - __fdividef(2.f, __expf(2.f*x) + 1.f);
}
// 128-long dot: w = global row (16B aligned), s = LDS row (broadcast across threads)
__device__ __forceinline__ float dot128(const float* __restrict__ w, const float* s){
  float a0=0.f,a1=0.f,a2=0.f,a3=0.f;
  #pragma unroll
  for (int e=0;e<32;++e){
    f32x4 w4 = *(const f32x4*)(w + (e<<2));
    f32x4 x4 = *(const f32x4*)(s + (e<<2));
    a0 = fmaf(w4[0],x4[0],a0); a1 = fmaf(w4[1],x4[1],a1);
    a2 = fmaf(w4[2],x4[2],a2); a3 = fmaf(w4[3],x4[3],a3);
  }
  return (a0+a1)+(a2+a3);
}

// ---------------- prep 1: weights f32->bf16 + mask dtype probe ----------------
__global__ void prep_weights(const float* __restrict__ wih, const float* __restrict__ whh,
                             const float* __restrict__ wks, const float* __restrict__ wvs,
                             const int* __restrict__ mask_i,
                             unsigned short* __restrict__ dst, int* __restrict__ flags){
  const int tid = blockIdx.x*256 + threadIdx.x;     // 512*256 = 131072 elems exactly
  if (tid < 49152)        dst[tid] = f2bf(wih[tid]);
  else if (tid < 98304)   dst[tid] = f2bf(whh[tid-49152]);
  else if (tid < 114688)  dst[tid] = f2bf(wks[tid-98304]);
  else                    dst[tid] = f2bf(wvs[tid-114688]);
  if (blockIdx.x==0 && threadIdx.x==0){
    // int32 bool array -> every word is 0/1. byte-packed bools -> words like 0x01000101.
    int bytemode = 0;
    for (int i=0;i<64;++i){ unsigned v = (unsigned)mask_i[i]; if (v > 1u) bytemode = 1; }
    flags[0] = bytemode;
  }
}

// ---------------- prep 2: q = src @ w_qs^T  (8192 x 128) ----------------
__global__ void prep_q(const float* __restrict__ src, const float* __restrict__ wqs,
                       float* __restrict__ q_ws){
  __shared__ __align__(16) float s_lds[32*128];
  const int t = threadIdx.x;                  // 128 threads
  const size_t r0 = (size_t)blockIdx.x * 32;  // 32 rows per block
  for (int it=0; it<32; ++it){
    const int idx = t + it*128;
    s_lds[idx] = src[r0*128 + idx];
  }
  __syncthreads();
  const float* wr = wqs + t*128;
  for (int rg=0; rg<8; ++rg){
    float a0=0.f,a1=0.f,a2=0.f,a3=0.f;
    #pragma unroll
    for (int e=0;e<32;++e){
      f32x4 w4 = *(const f32x4*)(wr + (e<<2));
      f32x4 x0 = *(const f32x4*)&s_lds[(rg*4+0)*128 + (e<<2)];
      f32x4 x1 = *(const f32x4*)&s_lds[(rg*4+1)*128 + (e<<2)];
      f32x4 x2 = *(const f32x4*)&s_lds[(rg*4+2)*128 + (e<<2)];
      f32x4 x3 = *(const f32x4*)&s_lds[(rg*4+3)*128 + (e<<2)];
      #pragma unroll
      for (int k=0;k<4;++k){
        a0 = fmaf(w4[k],x0[k],a0); a1 = fmaf(w4[k],x1[k],a1);
        a2 = fmaf(w4[k],x2[k],a2); a3 = fmaf(w4[k],x3[k],a3);
      }
    }
    q_ws[(r0+rg*4+0)*128 + t] = a0;
    q_ws[(r0+rg*4+1)*128 + t] = a1;
    q_ws[(r0+rg*4+2)*128 + t] = a2;
    q_ws[(r0+rg*4+3)*128 + t] = a3;
  }
}

// ---------------- main fused kernel: 4 sources per block ----------------
__global__ __launch_bounds__(256, 2) void cawn_main(
    const float* __restrict__ src, const float* __restrict__ ngh,
    const float* __restrict__ hid, const int* __restrict__ mask_i,
    const float* __restrict__ bih, const float* __restrict__ bhh,
    const float* __restrict__ fcw, const float* __restrict__ fcb,
    const float* __restrict__ lng, const float* __restrict__ lnb,
    const float* __restrict__ m1w, const float* __restrict__ m1b,
    const float* __restrict__ m2w, const float* __restrict__ m2b,
    const unsigned short* __restrict__ wihb, const unsigned short* __restrict__ whhb,
    const unsigned short* __restrict__ wksb, const unsigned short* __restrict__ wvsb,
    const float* __restrict__ q_ws, const int* __restrict__ flags,
    float* __restrict__ out)
{
  __shared__ __align__(16) unsigned short bufA[64*128];  // x  -> seq
  __shared__ __align__(16) unsigned short bufB[64*128];  // h  -> k
  __shared__ __align__(16) unsigned short bufC[64*128];  // v
  __shared__ __align__(16) float q_lds[128];
  __shared__ float sc_lds[2][64];
  __shared__ __align__(16) float src_lds[4][128];
  __shared__ __align__(16) float ao_lds[4][128];
  __shared__ __align__(16) float ep1[4][128];
  __shared__ __align__(16) float ep2[4][128];
  __shared__ int hflag[4];

  const int t    = threadIdx.x;
  const int wv   = t >> 6;
  const int lane = t & 63;
  const int l15  = lane & 15;
  const int lgrp = lane >> 4;
  const int gsrc0 = blockIdx.x * 4;
  const int mask_mode = flags[0];
  const f32x4 z4 = {0.f,0.f,0.f,0.f};

  // hoist biases for this thread's gate columns (cols = wv*32 + j*16 + l15)
  float bi_r[2], bi_z[2], bi_n[2], bh_r[2], bh_z[2], bh_n[2];
  #pragma unroll
  for (int j=0;j<2;++j){
    const int c = (wv<<5) + (j<<4) + l15;
    bi_r[j]=bih[c]; bi_z[j]=bih[128+c]; bi_n[j]=bih[256+c];
    bh_r[j]=bhh[c]; bh_z[j]=bhh[128+c]; bh_n[j]=bhh[256+c];
  }

  for (int sl=0; sl<4; ++sl){
    const int gsrc = gsrc0 + sl;
    const size_t base = (size_t)gsrc * 8192;   // 64 rows * 128 cols

    // ---- stage x,h (f32 global -> bf16 LDS, XOR-swizzled) ----
    bool hnz_local = false;
    #pragma unroll
    for (int it=0; it<8; ++it){
      const int f4  = t + it*256;              // 2048 float4s per buffer
      const int m   = f4 >> 5;
      const int col = (f4 & 31) << 2;
      f32x4 vx = *(const f32x4*)(ngh + base + (f4<<2));
      f32x4 vh = *(const f32x4*)(hid + base + (f4<<2));
      hnz_local = hnz_local || (vh[0]!=0.f)||(vh[1]!=0.f)||(vh[2]!=0.f)||(vh[3]!=0.f);
      const int idx = m*128 + (col ^ ((m&7)<<3));
      u16x4 px, ph;
      px[0]=f2bf(vx[0]); px[1]=f2bf(vx[1]); px[2]=f2bf(vx[2]); px[3]=f2bf(vx[3]);
      ph[0]=f2bf(vh[0]); ph[1]=f2bf(vh[1]); ph[2]=f2bf(vh[2]); ph[3]=f2bf(vh[3]);
      *(u16x4*)&bufA[idx] = px;
      *(u16x4*)&bufB[idx] = ph;
    }
    if (t < 128){
      q_lds[t]       = q_ws[(size_t)gsrc*128 + t];
      src_lds[sl][t] = src[(size_t)gsrc*128 + t];
    }
    { unsigned long long b = __ballot((int)hnz_local); if (lane==0) hflag[wv] = (b!=0ull)?1:0; }
    __syncthreads();
    const int hnz = hflag[0] | hflag[1] | hflag[2] | hflag[3];

    // ---- GRU matmuls: gi (+gh if h!=0). r,z gates share one accumulator ----
    f32x4 acc_rz[4][4], acc_ni[4][2], acc_nh[4][2];
    #pragma unroll
    for (int rt=0;rt<4;++rt){
      #pragma unroll
      for (int j=0;j<4;++j) acc_rz[rt][j] = z4;
      acc_ni[rt][0]=z4; acc_ni[rt][1]=z4; acc_nh[rt][0]=z4; acc_nh[rt][1]=z4;
    }
    #pragma unroll
    for (int kb=0;kb<4;++kb){
      const int kbase = (kb<<5) + (lgrp<<3);
      bf16x8 bI[6];
      #pragma unroll
      for (int j=0;j<2;++j){
        const int nc = (wv<<5)+(j<<4)+l15;
        bI[j]   = *(const bf16x8*)(wihb + nc*128 + kbase);
        bI[2+j] = *(const bf16x8*)(wihb + (128+nc)*128 + kbase);
        bI[4+j] = *(const bf16x8*)(wihb + (256+nc)*128 + kbase);
      }
      #pragma unroll
      for (int rt=0;rt<4;++rt){
        const int m   = (rt<<4) + l15;
        const int idx = m*128 + (kbase ^ ((m&7)<<3));
        bf16x8 ax = *(const bf16x8*)&bufA[idx];
        acc_rz[rt][0] = MFMA16(ax, bI[0], acc_rz[rt][0]);
        acc_rz[rt][1] = MFMA16(ax, bI[1], acc_rz[rt][1]);
        acc_rz[rt][2] = MFMA16(ax, bI[2], acc_rz[rt][2]);
        acc_rz[rt][3] = MFMA16(ax, bI[3], acc_rz[rt][3]);
        acc_ni[rt][0] = MFMA16(ax, bI[4], acc_ni[rt][0]);
        acc_ni[rt][1] = MFMA16(ax, bI[5], acc_ni[rt][1]);
      }
      if (hnz){
        bf16x8 bH[6];
        #pragma unroll
        for (int j=0;j<2;++j){
          const int nc = (wv<<5)+(j<<4)+l15;
          bH[j]   = *(const bf16x8*)(whhb + nc*128 + kbase);
          bH[2+j] = *(const bf16x8*)(whhb + (128+nc)*128 + kbase);
          bH[4+j] = *(const bf16x8*)(whhb + (256+nc)*128 + kbase);
        }
        #pragma unroll
        for (int rt=0;rt<4;++rt){
          const int m   = (rt<<4) + l15;
          const int idx = m*128 + (kbase ^ ((m&7)<<3));
          bf16x8 ah = *(const bf16x8*)&bufB[idx];
          acc_rz[rt][0] = MFMA16(ah, bH[0], acc_rz[rt][0]);
          acc_rz[rt][1] = MFMA16(ah, bH[1], acc_rz[rt][1]);
          acc_rz[rt][2] = MFMA16(ah, bH[2], acc_rz[rt][2]);
          acc_rz[rt][3] = MFMA16(ah, bH[3], acc_rz[rt][3]);
          acc_nh[rt][0] = MFMA16(ah, bH[4], acc_nh[rt][0]);
          acc_nh[rt][1] = MFMA16(ah, bH[5], acc_nh[rt][1]);
        }
      }
    }
    __syncthreads();   // all bufA(x) reads done before seq overwrites it

    // ---- GRU elementwise -> seq (bf16) into bufA ----
    #pragma unroll
    for (int rt=0;rt<4;++rt){
      #pragma unroll
      for (int j=0;j<2;++j){
        const int c  = (wv<<5) + (j<<4) + l15;
        const int mb = (rt<<4) + (lgrp<<2);
        #pragma unroll
        for (int r=0;r<4;++r){
          const int m = mb + r;
          const float rv = sigm(acc_rz[rt][j][r]   + bi_r[j] + bh_r[j]);
          const float zv = sigm(acc_rz[rt][2+j][r] + bi_z[j] + bh_z[j]);
          const float hn = acc_nh[rt][j][r] + bh_n[j];
          const float nv = tanhfast(acc_ni[rt][j][r] + bi_n[j] + rv*hn);
          const float hv = bf2f(bufB[m*128 + (c ^ ((m&7)<<3))]);
          const float sv = (1.f - zv)*nv + zv*hv;
          bufA[m*128 + (c ^ ((m&7)<<3))] = f2bf(sv);
        }
      }
    }
    __syncthreads();

    // ---- K/V projections ----
    f32x4 acc_k[4][2], acc_v[4][2];
    #pragma unroll
    for (int rt=0;rt<4;++rt){ acc_k[rt][0]=z4; acc_k[rt][1]=z4; acc_v[rt][0]=z4; acc_v[rt][1]=z4; }
    #pragma unroll
    for (int kb=0;kb<4;++kb){
      const int kbase = (kb<<5) + (lgrp<<3);
      bf16x8 bk[2], bv[2];
      #pragma unroll
      for (int j=0;j<2;++j){
        const int nc = (wv<<5)+(j<<4)+l15;
        bk[j] = *(const bf16x8*)(wksb + nc*128 + kbase);
        bv[j] = *(const bf16x8*)(wvsb + nc*128 + kbase);
      }
      #pragma unroll
      for (int rt=0;rt<4;++rt){
        const int m   = (rt<<4) + l15;
        bf16x8 as = *(const bf16x8*)&bufA[m*128 + (kbase ^ ((m&7)<<3))];
        acc_k[rt][0] = MFMA16(as, bk[0], acc_k[rt][0]);
        acc_k[rt][1] = MFMA16(as, bk[1], acc_k[rt][1]);
        acc_v[rt][0] = MFMA16(as, bv[0], acc_v[rt][0]);
        acc_v[rt][1] = MFMA16(as, bv[1], acc_v[rt][1]);
      }
    }
    // write k,v to LDS (bufB/bufC) — safe: bufB last read before previous barrier
    #pragma unroll
    for (int rt=0;rt<4;++rt){
      #pragma unroll
      for (int j=0;j<2;++j){
        const int c  = (wv<<5) + (j<<4) + l15;
        const int mb = (rt<<4) + (lgrp<<2);
        #pragma unroll
        for (int r=0;r<4;++r){
          const int m = mb + r;
          bufB[m*128 + (c ^ ((m&7)<<3))] = f2bf(acc_k[rt][j][r]);
          bufC[m*128 + (c ^ ((m&7)<<3))] = f2bf(acc_v[rt][j][r]);
        }
      }
    }
    __syncthreads();

    // ---- attention: scores ----
    if (t < 128){
      const int h = t>>6, jj = t&63;
      float acc = 0.f;
      #pragma unroll
      for (int c8=0;c8<8;++c8){
        const int cb = (h<<6) + (c8<<3);
        bf16x8 kc = *(const bf16x8*)&bufB[jj*128 + (cb ^ ((jj&7)<<3))];
        const f32x4 q0 = *(const f32x4*)&q_lds[cb];
        const f32x4 q1 = *(const f32x4*)&q_lds[cb+4];
        acc = fmaf(bf2f((unsigned short)kc[0]), q0[0], acc);
        acc = fmaf(bf2f((unsigned short)kc[1]), q0[1], acc);
        acc = fmaf(bf2f((unsigned short)kc[2]), q0[2], acc);
        acc = fmaf(bf2f((unsigned short)kc[3]), q0[3], acc);
        acc = fmaf(bf2f((unsigned short)kc[4]), q1[0], acc);
        acc = fmaf(bf2f((unsigned short)kc[5]), q1[1], acc);
        acc = fmaf(bf2f((unsigned short)kc[6]), q1[2], acc);
        acc = fmaf(bf2f((unsigned short)kc[7]), q1[3], acc);
      }
      bool msk;
      if (mask_mode == 0) msk = (mask_i[(size_t)gsrc*64 + jj] != 0);
      else                msk = (((const unsigned char*)mask_i)[(size_t)gsrc*64 + jj] != 0);
      sc_lds[h][jj] = msk ? -1e10f : acc*0.125f;
    }
    __syncthreads();
    // ---- softmax (wave 0 -> head 0, wave 1 -> head 1) ----
    if (t < 128){
      const int h = t>>6, jj = t&63;
      float s = sc_lds[h][jj];
      float mx = s;
      #pragma unroll
      for (int o=32;o>=1;o>>=1) mx = fmaxf(mx, __shfl_xor(mx,o));
      const float e = __expf(s - mx);
      float sum = e;
      #pragma unroll
      for (int o=32;o>=1;o>>=1) sum += __shfl_xor(sum,o);
      sc_lds[h][jj] = __fdividef(e, sum);
    }
    __syncthreads();
    // ---- PV ----
    if (t < 128){
      const int h = t>>6;
      float o = 0.f;
      for (int j=0;j<64;++j)
        o = fmaf(sc_lds[h][j], bf2f(bufC[j*128 + (t ^ ((j&7)<<3))]), o);
      ao_lds[sl][t] = o;
    }
    __syncthreads();   // protects bufA/B/C + sc_lds before next chunk
  }

  // ---------------- epilogue for the block's 4 sources ----------------
  const int d  = t & 127;
  const int sh = (t >> 7) << 1;   // this thread handles sources sh, sh+1
  // fc + bias + residual
  #pragma unroll
  for (int si=0; si<2; ++si){
    const int s = sh + si;
    float a = fcb[d] + dot128(fcw + d*128, &ao_lds[s][0]);
    a += src_lds[s][d];
    ep1[s][d] = a;
  }
  __syncthreads();
  // layernorm: wave wv handles source wv
  {
    const int s = wv;
    const float v0 = ep1[s][lane], v1 = ep1[s][64+lane];
    float sum = v0+v1, sq = v0*v0 + v1*v1;
    #pragma unroll
    for (int o=32;o>=1;o>>=1){ sum += __shfl_xor(sum,o); sq += __shfl_xor(sq,o); }
    const float mu  = sum * 0.0078125f;
    const float var = sq  * 0.0078125f - mu*mu;
    const float rs  = rsqrtf(var + 1e-5f);
    ep1[s][lane]    = (v0-mu)*rs*lng[lane]    + lnb[lane];
    ep1[s][64+lane] = (v1-mu)*rs*lng[64+lane] + lnb[64+lane];
  }
  __syncthreads();
  // merge fc1: cat([x_ln, src]) @ m1w^T, relu
  #pragma unroll
  for (int si=0; si<2; ++si){
    const int s = sh + si;
    float a = m1b[d];
    a += dot128(m1w + d*256,       &ep1[s][0]);
    a += dot128(m1w + d*256 + 128, &src_lds[s][0]);
    ep2[s][d] = fmaxf(a, 0.f);
  }
  __syncthreads();
  // merge fc2 -> out
  #pragma unroll
  for (int si=0; si<2; ++si){
    const int s = sh + si;
    float a = m2b[d] + dot128(m2w + d*128, &ep2[s][0]);
    out[(size_t)(gsrc0+s)*128 + d] = a;
  }
}

extern "C" void kernel_launch(void* const* d_in, const int* in_sizes, int n_in,
                              void* d_out, int out_size, void* d_ws, size_t ws_size,
                              hipStream_t stream){
  const float* src = (const float*)d_in[0];
  const float* ngh = (const float*)d_in[1];
  const float* hid = (const float*)d_in[2];
  const int*   msk = (const int*)  d_in[3];
  const float* wih = (const float*)d_in[4];
  const float* whh = (const float*)d_in[5];
  const float* bih = (const float*)d_in[6];
  const float* bhh = (const float*)d_in[7];
  const float* wqs = (const float*)d_in[8];
  const float* wks = (const float*)d_in[9];
  const float* wvs = (const float*)d_in[10];
  const float* fcw = (const float*)d_in[11];
  const float* fcb = (const float*)d_in[12];
  const float* lng = (const float*)d_in[13];
  const float* lnb = (const float*)d_in[14];
  const float* m1w = (const float*)d_in[15];
  const float* m1b = (const float*)d_in[16];
  const float* m2w = (const float*)d_in[17];
  const float* m2b = (const float*)d_in[18];
  float* out = (float*)d_out;

  unsigned short* wbf = (unsigned short*)d_ws;              // 131072 bf16 = 262144 B
  int*   flags = (int*)  ((char*)d_ws + 262144);
  float* q_ws  = (float*)((char*)d_ws + 262400);            // 8192*128 f32 = 4 MB

  prep_weights<<<512, 256, 0, stream>>>(wih, whh, wks, wvs, msk, wbf, flags);
  prep_q      <<<256, 128, 0, stream>>>(src, wqs, q_ws);
  cawn_main   <<<2048, 256, 0, stream>>>(src, ngh, hid, msk, bih, bhh,
                                         fcw, fcb, lng, lnb, m1w, m1b, m2w, m2b,
                                         wbf, wbf+49152, wbf+98304, wbf+114688,
                                         q_ws, flags, out);
}